// Round 1
// baseline (3094.563 us; speedup 1.0000x reference)
//
#include <hip/hip_runtime.h>

#define TT 256
#define HPAD 20   // padded row stride (floats) for hT: 80B, 16B-aligned, bank-spread

__device__ __forceinline__ float sig_(float x) { return 1.0f / (1.0f + __expf(-x)); }
__device__ __forceinline__ float th_(float x)  { return 1.0f - 2.0f / (__expf(2.0f * x) + 1.0f); }

#define FMA4(bb, hcomp)                                                        \
  acc[bb][0] += (hcomp) * wv.x; acc[bb][1] += (hcomp) * wv.y;                  \
  acc[bb][2] += (hcomp) * wv.z; acc[bb][3] += (hcomp) * wv.w;

// ---------------- Layer 0: x[B,T,4] -> h1 sequence in ws ----------------
__global__ __launch_bounds__(256) void lstm_l0(
    const float* __restrict__ x, const float* __restrict__ Wih,
    const float* __restrict__ Whh, const float* __restrict__ bih,
    const float* __restrict__ bhh, float* __restrict__ h1ws)
{
  extern __shared__ float smem[];
  float* WT = smem;            // [64][256]  WT[k][hu*4+g] = Whh[g*64+hu][k]
  float* hT = smem + 64 * 256; // [64][HPAD] hT[k][b]
  const int tid = threadIdx.x;
  const int bg = tid >> 6, hu = tid & 63;
  const int wb = blockIdx.x * 16;

  for (int i = tid; i < 64 * 256; i += 256) {
    int col = i & 255, k = i >> 8;
    int j = (col & 3) * 64 + (col >> 2);
    WT[k * 256 + col] = Whh[j * 64 + k];
  }
  float wih[4][4], cb[4];
#pragma unroll
  for (int g = 0; g < 4; ++g) {
    int j = g * 64 + hu;
    cb[g] = bih[j] + bhh[j];
#pragma unroll
    for (int d = 0; d < 4; ++d) wih[g][d] = Wih[j * 4 + d];
  }
  float hreg[4] = {0.f, 0.f, 0.f, 0.f}, creg[4] = {0.f, 0.f, 0.f, 0.f};
  float4 xb[4];
#pragma unroll
  for (int b = 0; b < 4; ++b)
    xb[b] = *(const float4*)(x + ((size_t)(wb + (bg << 2) + b) * TT) * 4);
  __syncthreads(); // WT ready

  for (int t = 0; t < TT; ++t) {
    *(float4*)(hT + hu * HPAD + (bg << 2)) =
        make_float4(hreg[0], hreg[1], hreg[2], hreg[3]);
    __syncthreads();
    float acc[4][4];
#pragma unroll
    for (int b = 0; b < 4; ++b) {
#pragma unroll
      for (int g = 0; g < 4; ++g)
        acc[b][g] = cb[g] + xb[b].x * wih[g][0] + xb[b].y * wih[g][1] +
                    xb[b].z * wih[g][2] + xb[b].w * wih[g][3];
    }
    int t1 = (t + 1 < TT) ? t + 1 : t; // prefetch next step's x
#pragma unroll
    for (int b = 0; b < 4; ++b)
      xb[b] = *(const float4*)(x + ((size_t)(wb + (bg << 2) + b) * TT + t1) * 4);
#pragma unroll 16
    for (int k = 0; k < 64; ++k) {
      float4 wv = *(const float4*)(WT + k * 256 + (hu << 2));
      float4 hv = *(const float4*)(hT + k * HPAD + (bg << 2));
      FMA4(0, hv.x) FMA4(1, hv.y) FMA4(2, hv.z) FMA4(3, hv.w)
    }
#pragma unroll
    for (int b = 0; b < 4; ++b) {
      float ii = sig_(acc[b][0]);
      float ff = sig_(acc[b][1]);
      float gg = th_(acc[b][2]);
      float oo = sig_(acc[b][3]);
      float c = ff * creg[b] + ii * gg;
      float h = oo * th_(c);
      creg[b] = c; hreg[b] = h;
      h1ws[((size_t)(wb + (bg << 2) + b) * TT + t) * 64 + hu] = h;
    }
    __syncthreads();
  }
}

// ---------------- Layer 1 (+ FC): cat[h1;h2prev](128) x WT[128][256] ----------------
__global__ __launch_bounds__(256) void lstm_l1fc(
    const float* __restrict__ h1ws, const float* __restrict__ Wih,
    const float* __restrict__ Whh, const float* __restrict__ bih,
    const float* __restrict__ bhh, const float* __restrict__ Wfc,
    const float* __restrict__ bfc, float* __restrict__ out)
{
  extern __shared__ float smem[];
  float* WT = smem;             // [128][256]
  float* hT = smem + 128 * 256; // [128][HPAD] rows 0..63 = h1[t], 64..127 = h2prev
  const int tid = threadIdx.x;
  const int bg = tid >> 6, hu = tid & 63;
  const int wb = blockIdx.x * 16;

  for (int i = tid; i < 128 * 256; i += 256) {
    int col = i & 255, k = i >> 8;
    int j = (col & 3) * 64 + (col >> 2);
    WT[k * 256 + col] = (k < 64) ? Wih[j * 64 + k] : Whh[j * 64 + (k - 64)];
  }
  float cb[4];
#pragma unroll
  for (int g = 0; g < 4; ++g) { int j = g * 64 + hu; cb[g] = bih[j] + bhh[j]; }
  const float wfc = Wfc[hu];
  const float bf0 = bfc[0];
  float hreg[4] = {0.f, 0.f, 0.f, 0.f}, creg[4] = {0.f, 0.f, 0.f, 0.f};
  float ld[4];
#pragma unroll
  for (int r = 0; r < 4; ++r) {
    int idx = tid + (r << 8);
    ld[r] = h1ws[((size_t)(wb + (idx >> 6)) * TT) * 64 + (idx & 63)];
  }
  __syncthreads(); // WT ready

  for (int t = 0; t < TT; ++t) {
#pragma unroll
    for (int r = 0; r < 4; ++r) { // stage h1[t] transposed
      int idx = tid + (r << 8);
      hT[(idx & 63) * HPAD + (idx >> 6)] = ld[r];
    }
    *(float4*)(hT + (64 + hu) * HPAD + (bg << 2)) =
        make_float4(hreg[0], hreg[1], hreg[2], hreg[3]);
    int t1 = (t + 1 < TT) ? t + 1 : t; // prefetch next h1
#pragma unroll
    for (int r = 0; r < 4; ++r) {
      int idx = tid + (r << 8);
      ld[r] = h1ws[((size_t)(wb + (idx >> 6)) * TT + t1) * 64 + (idx & 63)];
    }
    __syncthreads();
    float acc[4][4];
#pragma unroll
    for (int b = 0; b < 4; ++b) {
#pragma unroll
      for (int g = 0; g < 4; ++g) acc[b][g] = cb[g];
    }
#pragma unroll 16
    for (int k = 0; k < 128; ++k) {
      float4 wv = *(const float4*)(WT + k * 256 + (hu << 2));
      float4 hv = *(const float4*)(hT + k * HPAD + (bg << 2));
      FMA4(0, hv.x) FMA4(1, hv.y) FMA4(2, hv.z) FMA4(3, hv.w)
    }
#pragma unroll
    for (int b = 0; b < 4; ++b) {
      float ii = sig_(acc[b][0]);
      float ff = sig_(acc[b][1]);
      float gg = th_(acc[b][2]);
      float oo = sig_(acc[b][3]);
      float c = ff * creg[b] + ii * gg;
      float h = oo * th_(c);
      creg[b] = c; hreg[b] = h;
    }
    __syncthreads();
  }
  // FC: out[b] = sum_hu h2last[b][hu]*Wfc[hu] + bfc  (reduce across the 64 hu lanes)
  float p[4];
#pragma unroll
  for (int b = 0; b < 4; ++b) p[b] = hreg[b] * wfc;
#pragma unroll
  for (int off = 32; off >= 1; off >>= 1) {
#pragma unroll
    for (int b = 0; b < 4; ++b) p[b] += __shfl_xor(p[b], off, 64);
  }
  if ((tid & 63) == 0) {
#pragma unroll
    for (int b = 0; b < 4; ++b) out[wb + (bg << 2) + b] = p[b] + bf0;
  }
}

extern "C" void kernel_launch(void* const* d_in, const int* in_sizes, int n_in,
                              void* d_out, int out_size, void* d_ws, size_t ws_size,
                              hipStream_t stream) {
  const float* x    = (const float*)d_in[0];
  const float* Wih0 = (const float*)d_in[1];
  const float* Whh0 = (const float*)d_in[2];
  const float* bih0 = (const float*)d_in[3];
  const float* bhh0 = (const float*)d_in[4];
  const float* Wih1 = (const float*)d_in[5];
  const float* Whh1 = (const float*)d_in[6];
  const float* bih1 = (const float*)d_in[7];
  const float* bhh1 = (const float*)d_in[8];
  const float* Wfc  = (const float*)d_in[9];
  const float* bfc  = (const float*)d_in[10];
  float* out = (float*)d_out;
  float* ws  = (float*)d_ws;

  const int B = in_sizes[0] / (TT * 4); // 4096
  const size_t ldsA = (size_t)(64 * 256 + 64 * HPAD) * sizeof(float);   // ~69 KB
  const size_t ldsB = (size_t)(128 * 256 + 128 * HPAD) * sizeof(float); // ~138 KB
  hipFuncSetAttribute((const void*)lstm_l0,
                      hipFuncAttributeMaxDynamicSharedMemorySize, (int)ldsA);
  hipFuncSetAttribute((const void*)lstm_l1fc,
                      hipFuncAttributeMaxDynamicSharedMemorySize, (int)ldsB);

  // batch-chunk so h1 staging fits in ws
  const size_t perB = (size_t)TT * 64 * sizeof(float);
  int capB = (int)((ws_size / perB) & ~(size_t)15);
  if (capB < 16) capB = 16;
  if (capB > B) capB = B;

  for (int b0 = 0; b0 < B; b0 += capB) {
    int cbn = (B - b0 < capB) ? (B - b0) : capB;
    dim3 grid(cbn / 16), block(256);
    lstm_l0<<<grid, block, ldsA, stream>>>(x + (size_t)b0 * TT * 4, Wih0, Whh0,
                                           bih0, bhh0, ws);
    lstm_l1fc<<<grid, block, ldsB, stream>>>(ws, Wih1, Whh1, bih1, bhh1, Wfc,
                                             bfc, out + b0);
  }
}

// Round 2
// 2838.745 us; speedup vs baseline: 1.0901x; 1.0901x over previous
//
#include <hip/hip_runtime.h>

#define TT 256
#define HH 64

__device__ __forceinline__ float sig_(float x) { return 1.0f / (1.0f + __expf(-x)); }
__device__ __forceinline__ float th_(float x)  { return 1.0f - 2.0f / (__expf(2.0f * x) + 1.0f); }

// ---------------- Layer 0: x[B,T,4] -> h1 sequence in ws ([t][Bc][64]) ---------
// 512 threads? No: 256 threads = 4 waves. Wave w owns K-slice [w*16,w*16+16) of Whh,
// weights in VGPRs. Batch-duty: wave w does activations for batches 2w, 2w+1.
__global__ __launch_bounds__(256, 2) void lstm_l0(
    const float* __restrict__ x, const float* __restrict__ Wih,
    const float* __restrict__ Whh, const float* __restrict__ bih,
    const float* __restrict__ bhh, float* __restrict__ h1ws, int Bc)
{
  __shared__ float  hbuf[2][8][72];    // [buf][b][k 0..63 +pad] h_prev, b-major
  __shared__ float4 pbuf[4][64][8];    // [wave][hu][unit b^(hu&7)] partial gates
  const int tid = threadIdx.x;
  const int w = tid >> 6, hu = tid & 63;
  const int wb = blockIdx.x * 8;
  const int kb = w * 16;
  const int b0 = 2 * w;

  // Whh slice -> regs: w4[j][g] = Whh[g*64+hu][kb+4j .. +3]
  float4 w4[4][4];
#pragma unroll
  for (int j = 0; j < 4; ++j)
#pragma unroll
    for (int g = 0; g < 4; ++g)
      w4[j][g] = *(const float4*)(Whh + (size_t)(g * 64 + hu) * 64 + kb + 4 * j);
  float4 wih[4];
  float cb[4];
#pragma unroll
  for (int g = 0; g < 4; ++g) {
    wih[g] = *(const float4*)(Wih + (size_t)(g * 64 + hu) * 4);
    cb[g] = bih[g * 64 + hu] + bhh[g * 64 + hu];
  }
  for (int i = tid; i < 8 * 72; i += 256) hbuf[0][i / 72][i % 72] = 0.f;

  float creg[2] = {0.f, 0.f};
  float4 xf[2];
#pragma unroll
  for (int i = 0; i < 2; ++i)
    xf[i] = *(const float4*)(x + (size_t)(wb + b0 + i) * TT * 4);
  __syncthreads();

  for (int t = 0; t < TT; ++t) {
    const int cur = t & 1, nxt = cur ^ 1;
    const int t1 = (t + 1 < TT) ? t + 1 : t;
    float4 xn[2];
#pragma unroll
    for (int i = 0; i < 2; ++i)
      xn[i] = *(const float4*)(x + ((size_t)(wb + b0 + i) * TT + t1) * 4);

    // phase A: partial gates over this wave's K-slice (h via LDS broadcast)
    float acc[8][4];
#pragma unroll
    for (int b = 0; b < 8; ++b)
#pragma unroll
      for (int g = 0; g < 4; ++g) acc[b][g] = 0.f;
#pragma unroll
    for (int j = 0; j < 4; ++j) {
#pragma unroll
      for (int b = 0; b < 8; ++b) {
        float4 hv = *(const float4*)&hbuf[cur][b][kb + 4 * j];
#pragma unroll
        for (int g = 0; g < 4; ++g)
          acc[b][g] += hv.x * w4[j][g].x + hv.y * w4[j][g].y +
                       hv.z * w4[j][g].z + hv.w * w4[j][g].w;
      }
    }
    // phase B: publish partials (XOR-swizzled units -> conflict-free)
#pragma unroll
    for (int b = 0; b < 8; ++b)
      pbuf[w][hu][b ^ (hu & 7)] =
          make_float4(acc[b][0], acc[b][1], acc[b][2], acc[b][3]);
    __syncthreads();
    // phase C: duty batches — gather partials, add x+bias, activations
#pragma unroll
    for (int i = 0; i < 2; ++i) {
      const int b = b0 + i;
      float s0 = cb[0], s1 = cb[1], s2 = cb[2], s3 = cb[3];
      const float4 xv = xf[i];
      s0 += xv.x * wih[0].x + xv.y * wih[0].y + xv.z * wih[0].z + xv.w * wih[0].w;
      s1 += xv.x * wih[1].x + xv.y * wih[1].y + xv.z * wih[1].z + xv.w * wih[1].w;
      s2 += xv.x * wih[2].x + xv.y * wih[2].y + xv.z * wih[2].z + xv.w * wih[2].w;
      s3 += xv.x * wih[3].x + xv.y * wih[3].y + xv.z * wih[3].z + xv.w * wih[3].w;
#pragma unroll
      for (int wp = 0; wp < 4; ++wp) {
        float4 p;
        if (wp == w) p = make_float4(acc[b][0], acc[b][1], acc[b][2], acc[b][3]);
        else         p = pbuf[wp][hu][b ^ (hu & 7)];
        s0 += p.x; s1 += p.y; s2 += p.z; s3 += p.w;
      }
      const float ii = sig_(s0), ff = sig_(s1), gg = th_(s2), oo = sig_(s3);
      const float c = ff * creg[i] + ii * gg;
      const float h = oo * th_(c);
      creg[i] = c;
      hbuf[nxt][b][hu] = h;
      h1ws[((size_t)t * Bc + wb + b) * 64 + hu] = h;
    }
    xf[0] = xn[0]; xf[1] = xn[1];
    __syncthreads();
  }
}

// ---------------- Layer 1 + FC: K=128 (h1 | h2prev), same structure ------------
__global__ __launch_bounds__(256, 2) void lstm_l1fc(
    const float* __restrict__ h1ws, const float* __restrict__ Wih,
    const float* __restrict__ Whh, const float* __restrict__ bih,
    const float* __restrict__ bhh, const float* __restrict__ Wfc,
    const float* __restrict__ bfc, float* __restrict__ out, int Bc)
{
  __shared__ float  hbuf[2][8][136];   // [buf][b][k: 0..63 h1[t], 64..127 h2prev, pad]
  __shared__ float4 pbuf[4][64][8];
  const int tid = threadIdx.x;
  const int w = tid >> 6, hu = tid & 63;
  const int wb = blockIdx.x * 8;
  const int kb = w * 32;
  const int b0 = 2 * w;

  // weight slice -> regs: k<64 from Wih1, k>=64 from Whh1
  float4 w4[8][4];
#pragma unroll
  for (int j = 0; j < 8; ++j) {
    const int k = kb + 4 * j;
#pragma unroll
    for (int g = 0; g < 4; ++g) {
      const float* src = (k < 64)
          ? (Wih + (size_t)(g * 64 + hu) * 64 + k)
          : (Whh + (size_t)(g * 64 + hu) * 64 + (k - 64));
      w4[j][g] = *(const float4*)src;
    }
  }
  float cb[4];
#pragma unroll
  for (int g = 0; g < 4; ++g) cb[g] = bih[g * 64 + hu] + bhh[g * 64 + hu];
  const float wfc = Wfc[hu];
  const float bf0 = bfc[0];

  // zero h2 columns of buf0; stage h1[t=0] into cols 0..63 (disjoint -> no race)
  for (int i = tid; i < 8 * 72; i += 256) hbuf[0][i / 72][64 + i % 72] = 0.f;
  {
    const float2 v = *(const float2*)(h1ws + (size_t)wb * 64 + 2 * tid);
    *(float2*)&hbuf[0][tid >> 5][(2 * tid) & 63] = v;
  }
  float creg[2] = {0.f, 0.f}, hlast[2] = {0.f, 0.f};
  __syncthreads();

  for (int t = 0; t < TT; ++t) {
    const int cur = t & 1, nxt = cur ^ 1;
    const int t1 = (t + 1 < TT) ? t + 1 : t;
    // prefetch next h1 tile (consumed in phase B)
    const float2 pre = *(const float2*)(h1ws + ((size_t)t1 * Bc + wb) * 64 + 2 * tid);

    // phase A: partial gates over K-slice
    float acc[8][4];
#pragma unroll
    for (int b = 0; b < 8; ++b)
#pragma unroll
      for (int g = 0; g < 4; ++g) acc[b][g] = 0.f;
#pragma unroll
    for (int j = 0; j < 8; ++j) {
#pragma unroll
      for (int b = 0; b < 8; ++b) {
        float4 hv = *(const float4*)&hbuf[cur][b][kb + 4 * j];
#pragma unroll
        for (int g = 0; g < 4; ++g)
          acc[b][g] += hv.x * w4[j][g].x + hv.y * w4[j][g].y +
                       hv.z * w4[j][g].z + hv.w * w4[j][g].w;
      }
    }
    // phase B: publish partials + stage h1[t+1]
#pragma unroll
    for (int b = 0; b < 8; ++b)
      pbuf[w][hu][b ^ (hu & 7)] =
          make_float4(acc[b][0], acc[b][1], acc[b][2], acc[b][3]);
    *(float2*)&hbuf[nxt][tid >> 5][(2 * tid) & 63] = pre;
    __syncthreads();
    // phase C: duty batches
#pragma unroll
    for (int i = 0; i < 2; ++i) {
      const int b = b0 + i;
      float s0 = cb[0], s1 = cb[1], s2 = cb[2], s3 = cb[3];
#pragma unroll
      for (int wp = 0; wp < 4; ++wp) {
        float4 p;
        if (wp == w) p = make_float4(acc[b][0], acc[b][1], acc[b][2], acc[b][3]);
        else         p = pbuf[wp][hu][b ^ (hu & 7)];
        s0 += p.x; s1 += p.y; s2 += p.z; s3 += p.w;
      }
      const float ii = sig_(s0), ff = sig_(s1), gg = th_(s2), oo = sig_(s3);
      const float c = ff * creg[i] + ii * gg;
      const float h = oo * th_(c);
      creg[i] = c; hlast[i] = h;
      hbuf[nxt][b][64 + hu] = h;
    }
    __syncthreads();
  }
  // FC epilogue: out[b] = sum_hu h2_last[b][hu]*Wfc[hu] + bfc
  float p0 = hlast[0] * wfc, p1 = hlast[1] * wfc;
#pragma unroll
  for (int off = 32; off >= 1; off >>= 1) {
    p0 += __shfl_xor(p0, off, 64);
    p1 += __shfl_xor(p1, off, 64);
  }
  if (hu == 0) {
    out[wb + b0]     = p0 + bf0;
    out[wb + b0 + 1] = p1 + bf0;
  }
}

extern "C" void kernel_launch(void* const* d_in, const int* in_sizes, int n_in,
                              void* d_out, int out_size, void* d_ws, size_t ws_size,
                              hipStream_t stream) {
  const float* x    = (const float*)d_in[0];
  const float* Wih0 = (const float*)d_in[1];
  const float* Whh0 = (const float*)d_in[2];
  const float* bih0 = (const float*)d_in[3];
  const float* bhh0 = (const float*)d_in[4];
  const float* Wih1 = (const float*)d_in[5];
  const float* Whh1 = (const float*)d_in[6];
  const float* bih1 = (const float*)d_in[7];
  const float* bhh1 = (const float*)d_in[8];
  const float* Wfc  = (const float*)d_in[9];
  const float* bfc  = (const float*)d_in[10];
  float* out = (float*)d_out;
  float* ws  = (float*)d_ws;

  const int B = in_sizes[0] / (TT * 4); // 4096
  // chunk batches so h1 ([T][Bc][64] f32) fits in ws
  const size_t perB = (size_t)TT * 64 * sizeof(float);
  int capB = (int)((ws_size / perB) & ~(size_t)7);
  if (capB < 8) capB = 8;
  if (capB > B) capB = B;

  for (int b0 = 0; b0 < B; b0 += capB) {
    const int cbn = (B - b0 < capB) ? (B - b0) : capB;
    dim3 grid(cbn / 8), block(256);
    lstm_l0<<<grid, block, 0, stream>>>(x + (size_t)b0 * TT * 4, Wih0, Whh0,
                                        bih0, bhh0, ws, cbn);
    lstm_l1fc<<<grid, block, 0, stream>>>(ws, Wih1, Whh1, bih1, bhh1, Wfc, bfc,
                                          out + b0, cbn);
  }
}

// Round 3
// 1935.966 us; speedup vs baseline: 1.5985x; 1.4663x over previous
//
#include <hip/hip_runtime.h>

#define TT 256
#define HH 64

__device__ __forceinline__ float sig_(float x) { return 1.0f / (1.0f + __expf(-x)); }
__device__ __forceinline__ float th_(float x)  { return 1.0f - 2.0f / (__expf(2.0f * x) + 1.0f); }

// ---------------- Layer 0: x[B,T,4] -> h1 sequence in ws ([t][Bc][64]) ---------
// 256 threads = 4 waves. Wave w owns K-slice [w*16,w*16+16) of Whh, weights in
// VGPRs. Batch-duty: wave w does activations for batches 2w, 2w+1.
// NOTE: phase C reads ALL partials (incl. own wave's) from pbuf — never index
// the acc[][] register array with a runtime value (rule #20: it demotes acc to
// scratch; this was the R2 perf bug: VGPR_Count 116, 3-4x VALU inflation).
__global__ __launch_bounds__(256, 2) void lstm_l0(
    const float* __restrict__ x, const float* __restrict__ Wih,
    const float* __restrict__ Whh, const float* __restrict__ bih,
    const float* __restrict__ bhh, float* __restrict__ h1ws, int Bc)
{
  __shared__ float  hbuf[2][8][72];    // [buf][b][k 0..63 +pad] h_prev, b-major
  __shared__ float4 pbuf[4][64][8];    // [wave][hu][slot b^(hu&7)] partial gates
  const int tid = threadIdx.x;
  const int w = tid >> 6, hu = tid & 63;
  const int wb = blockIdx.x * 8;
  const int kb = w * 16;
  const int b0 = 2 * w;

  // Whh slice -> regs: w4[j][g] = Whh[g*64+hu][kb+4j .. +3]
  float4 w4[4][4];
#pragma unroll
  for (int j = 0; j < 4; ++j)
#pragma unroll
    for (int g = 0; g < 4; ++g)
      w4[j][g] = *(const float4*)(Whh + (size_t)(g * 64 + hu) * 64 + kb + 4 * j);
  float4 wih[4];
  float cb[4];
#pragma unroll
  for (int g = 0; g < 4; ++g) {
    wih[g] = *(const float4*)(Wih + (size_t)(g * 64 + hu) * 4);
    cb[g] = bih[g * 64 + hu] + bhh[g * 64 + hu];
  }
  for (int i = tid; i < 8 * 72; i += 256) hbuf[0][i / 72][i % 72] = 0.f;

  float creg[2] = {0.f, 0.f};
  float4 xf[2];
#pragma unroll
  for (int i = 0; i < 2; ++i)
    xf[i] = *(const float4*)(x + (size_t)(wb + b0 + i) * TT * 4);
  __syncthreads();

  for (int t = 0; t < TT; ++t) {
    const int cur = t & 1, nxt = cur ^ 1;
    const int t1 = (t + 1 < TT) ? t + 1 : t;
    float4 xn[2];
#pragma unroll
    for (int i = 0; i < 2; ++i)
      xn[i] = *(const float4*)(x + ((size_t)(wb + b0 + i) * TT + t1) * 4);

    // phase A: partial gates over this wave's K-slice (h via LDS broadcast)
    float acc[8][4];
#pragma unroll
    for (int b = 0; b < 8; ++b)
#pragma unroll
      for (int g = 0; g < 4; ++g) acc[b][g] = 0.f;
#pragma unroll
    for (int j = 0; j < 4; ++j) {
#pragma unroll
      for (int b = 0; b < 8; ++b) {
        float4 hv = *(const float4*)&hbuf[cur][b][kb + 4 * j];
#pragma unroll
        for (int g = 0; g < 4; ++g)
          acc[b][g] += hv.x * w4[j][g].x + hv.y * w4[j][g].y +
                       hv.z * w4[j][g].z + hv.w * w4[j][g].w;
      }
    }
    // phase B: publish partials (slot XOR keeps lanes bank-spread)
#pragma unroll
    for (int b = 0; b < 8; ++b)
      pbuf[w][hu][b ^ (hu & 7)] =
          make_float4(acc[b][0], acc[b][1], acc[b][2], acc[b][3]);
    __syncthreads();
    // phase C: duty batches — gather partials from LDS ONLY (compile-time reg idx)
#pragma unroll
    for (int i = 0; i < 2; ++i) {
      const int b = b0 + i;
      float s0 = cb[0], s1 = cb[1], s2 = cb[2], s3 = cb[3];
      const float4 xv = xf[i];
      s0 += xv.x * wih[0].x + xv.y * wih[0].y + xv.z * wih[0].z + xv.w * wih[0].w;
      s1 += xv.x * wih[1].x + xv.y * wih[1].y + xv.z * wih[1].z + xv.w * wih[1].w;
      s2 += xv.x * wih[2].x + xv.y * wih[2].y + xv.z * wih[2].z + xv.w * wih[2].w;
      s3 += xv.x * wih[3].x + xv.y * wih[3].y + xv.z * wih[3].z + xv.w * wih[3].w;
#pragma unroll
      for (int wp = 0; wp < 4; ++wp) {
        const float4 p = pbuf[wp][hu][b ^ (hu & 7)];
        s0 += p.x; s1 += p.y; s2 += p.z; s3 += p.w;
      }
      const float ii = sig_(s0), ff = sig_(s1), gg = th_(s2), oo = sig_(s3);
      const float c = ff * creg[i] + ii * gg;
      const float h = oo * th_(c);
      creg[i] = c;
      hbuf[nxt][b][hu] = h;
      h1ws[((size_t)t * Bc + wb + b) * 64 + hu] = h;
    }
    xf[0] = xn[0]; xf[1] = xn[1];
    __syncthreads();
  }
}

// ---------------- Layer 1 + FC: K=128 (h1 | h2prev), same structure ------------
__global__ __launch_bounds__(256, 2) void lstm_l1fc(
    const float* __restrict__ h1ws, const float* __restrict__ Wih,
    const float* __restrict__ Whh, const float* __restrict__ bih,
    const float* __restrict__ bhh, const float* __restrict__ Wfc,
    const float* __restrict__ bfc, float* __restrict__ out, int Bc)
{
  __shared__ float  hbuf[2][8][136];   // [buf][b][k: 0..63 h1[t], 64..127 h2prev, pad]
  __shared__ float4 pbuf[4][64][8];
  const int tid = threadIdx.x;
  const int w = tid >> 6, hu = tid & 63;
  const int wb = blockIdx.x * 8;
  const int kb = w * 32;
  const int b0 = 2 * w;

  // weight slice -> regs: k<64 from Wih1, k>=64 from Whh1
  float4 w4[8][4];
#pragma unroll
  for (int j = 0; j < 8; ++j) {
    const int k = kb + 4 * j;
#pragma unroll
    for (int g = 0; g < 4; ++g) {
      const float* src = (k < 64)
          ? (Wih + (size_t)(g * 64 + hu) * 64 + k)
          : (Whh + (size_t)(g * 64 + hu) * 64 + (k - 64));
      w4[j][g] = *(const float4*)src;
    }
  }
  float cb[4];
#pragma unroll
  for (int g = 0; g < 4; ++g) cb[g] = bih[g * 64 + hu] + bhh[g * 64 + hu];
  const float wfc = Wfc[hu];
  const float bf0 = bfc[0];

  // zero h2 columns of buf0; stage h1[t=0] into cols 0..63 (disjoint -> no race)
  for (int i = tid; i < 8 * 72; i += 256) hbuf[0][i / 72][64 + i % 72] = 0.f;
  {
    const float2 v = *(const float2*)(h1ws + (size_t)wb * 64 + 2 * tid);
    *(float2*)&hbuf[0][tid >> 5][(2 * tid) & 63] = v;
  }
  float creg[2] = {0.f, 0.f}, hlast[2] = {0.f, 0.f};
  __syncthreads();

  for (int t = 0; t < TT; ++t) {
    const int cur = t & 1, nxt = cur ^ 1;
    const int t1 = (t + 1 < TT) ? t + 1 : t;
    // prefetch next h1 tile (consumed in phase B)
    const float2 pre = *(const float2*)(h1ws + ((size_t)t1 * Bc + wb) * 64 + 2 * tid);

    // phase A: partial gates over K-slice
    float acc[8][4];
#pragma unroll
    for (int b = 0; b < 8; ++b)
#pragma unroll
      for (int g = 0; g < 4; ++g) acc[b][g] = 0.f;
#pragma unroll
    for (int j = 0; j < 8; ++j) {
#pragma unroll
      for (int b = 0; b < 8; ++b) {
        float4 hv = *(const float4*)&hbuf[cur][b][kb + 4 * j];
#pragma unroll
        for (int g = 0; g < 4; ++g)
          acc[b][g] += hv.x * w4[j][g].x + hv.y * w4[j][g].y +
                       hv.z * w4[j][g].z + hv.w * w4[j][g].w;
      }
    }
    // phase B: publish partials + stage h1[t+1]
#pragma unroll
    for (int b = 0; b < 8; ++b)
      pbuf[w][hu][b ^ (hu & 7)] =
          make_float4(acc[b][0], acc[b][1], acc[b][2], acc[b][3]);
    *(float2*)&hbuf[nxt][tid >> 5][(2 * tid) & 63] = pre;
    __syncthreads();
    // phase C: duty batches — partials from LDS only (no runtime reg indexing)
#pragma unroll
    for (int i = 0; i < 2; ++i) {
      const int b = b0 + i;
      float s0 = cb[0], s1 = cb[1], s2 = cb[2], s3 = cb[3];
#pragma unroll
      for (int wp = 0; wp < 4; ++wp) {
        const float4 p = pbuf[wp][hu][b ^ (hu & 7)];
        s0 += p.x; s1 += p.y; s2 += p.z; s3 += p.w;
      }
      const float ii = sig_(s0), ff = sig_(s1), gg = th_(s2), oo = sig_(s3);
      const float c = ff * creg[i] + ii * gg;
      const float h = oo * th_(c);
      creg[i] = c; hlast[i] = h;
      hbuf[nxt][b][64 + hu] = h;
    }
    __syncthreads();
  }
  // FC epilogue: out[b] = sum_hu h2_last[b][hu]*Wfc[hu] + bfc
  float p0 = hlast[0] * wfc, p1 = hlast[1] * wfc;
#pragma unroll
  for (int off = 32; off >= 1; off >>= 1) {
    p0 += __shfl_xor(p0, off, 64);
    p1 += __shfl_xor(p1, off, 64);
  }
  if (hu == 0) {
    out[wb + b0]     = p0 + bf0;
    out[wb + b0 + 1] = p1 + bf0;
  }
}

extern "C" void kernel_launch(void* const* d_in, const int* in_sizes, int n_in,
                              void* d_out, int out_size, void* d_ws, size_t ws_size,
                              hipStream_t stream) {
  const float* x    = (const float*)d_in[0];
  const float* Wih0 = (const float*)d_in[1];
  const float* Whh0 = (const float*)d_in[2];
  const float* bih0 = (const float*)d_in[3];
  const float* bhh0 = (const float*)d_in[4];
  const float* Wih1 = (const float*)d_in[5];
  const float* Whh1 = (const float*)d_in[6];
  const float* bih1 = (const float*)d_in[7];
  const float* bhh1 = (const float*)d_in[8];
  const float* Wfc  = (const float*)d_in[9];
  const float* bfc  = (const float*)d_in[10];
  float* out = (float*)d_out;
  float* ws  = (float*)d_ws;

  const int B = in_sizes[0] / (TT * 4); // 4096
  // chunk batches so h1 ([T][Bc][64] f32) fits in ws
  const size_t perB = (size_t)TT * 64 * sizeof(float);
  int capB = (int)((ws_size / perB) & ~(size_t)7);
  if (capB < 8) capB = 8;
  if (capB > B) capB = B;

  for (int b0 = 0; b0 < B; b0 += capB) {
    const int cbn = (B - b0 < capB) ? (B - b0) : capB;
    dim3 grid(cbn / 8), block(256);
    lstm_l0<<<grid, block, 0, stream>>>(x + (size_t)b0 * TT * 4, Wih0, Whh0,
                                        bih0, bhh0, ws, cbn);
    lstm_l1fc<<<grid, block, 0, stream>>>(ws, Wih1, Whh1, bih1, bhh1, Wfc, bfc,
                                          out + b0, cbn);
  }
}